// Round 6
// baseline (167.617 us; speedup 1.0000x reference)
//
#include <hip/hip_runtime.h>
#include <math.h>

#define N_    16
#define C_    256
#define H_    56
#define W_    56
#define HW_   3136          // H_*W_
#define NPIX  50176         // N_*HW_
#define OUTC  512
#define SPAN_ 2304          // C_*9
#define BLKPX 128           // conv block pixel tile
#define HSLOTS 256          // halo pixel slots (need 128 + 114 = 242)
#define HSTRIDE 80          // bytes per halo slot (32ch bf16 = 64B + 16B swizzle pad)

typedef unsigned short u16;
typedef unsigned int   u32;
typedef __attribute__((ext_vector_type(8))) short bf16x8;
typedef __attribute__((ext_vector_type(8))) unsigned short u16x8;
typedef __attribute__((ext_vector_type(4))) float f32x4;
typedef __attribute__((ext_vector_type(4))) unsigned short u16x4;

__device__ __forceinline__ u16 f2bf(float v) {
    u32 x = __float_as_uint(v);
    u32 r = (x + 0x7fffu + ((x >> 16) & 1u)) >> 16;   // RNE
    return (u16)r;
}

__device__ __forceinline__ int bucketf(float v, float b) {
    int idx = (int)floorf((v + b) / 2.5f);
    int r = idx % 8;
    return r < 0 ? -r : r;
}

// ---- Kernel P1+B1 fused: NCHW f32 -> NHWC bf16, tap maps g[9], sumsq s2 -----
__global__ __launch_bounds__(256) void prep_fused(const float* __restrict__ x,
                                                  const float* __restrict__ ah,
                                                  u16* __restrict__ xp,
                                                  float* __restrict__ g,
                                                  float* __restrict__ s2) {
    __shared__ float aL[SPAN_];          // 9216 B
    __shared__ u16 tl[64][68];           // 8704 B
    __shared__ float red[4][64][10];     // 10240 B
    int t = threadIdx.x;
    for (int j = t; j < SPAN_; j += 256) aL[j] = ah[j];

    int px0 = blockIdx.x * 64;
    int img = px0 / HW_;
    int hw0 = px0 - img * HW_;
    int px_l = t & 63;
    int cq   = t >> 6;                   // 0..3
    float pg[9];
#pragma unroll
    for (int kk = 0; kk < 9; ++kk) pg[kk] = 0.f;
    float ps = 0.f;
    __syncthreads();

    for (int cb0 = 0; cb0 < 4; ++cb0) {
        int c0 = cb0 * 64;
#pragma unroll
        for (int rep = 0; rep < 16; ++rep) {
            int c_l = rep * 4 + cq;
            float v = x[((size_t)(img * C_ + c0 + c_l)) * HW_ + hw0 + px_l];
            tl[px_l][c_l] = f2bf(v);
            const float* ac = &aL[(c0 + c_l) * 9];
#pragma unroll
            for (int kk = 0; kk < 9; ++kk) pg[kk] += ac[kk] * v;
            ps += v * v;
        }
        __syncthreads();
        int c4  = t & 15;
        int pxs = t >> 4;
#pragma unroll
        for (int rep = 0; rep < 4; ++rep) {
            int pl = rep * 16 + pxs;
            u16x4 v4 = *(const u16x4*)(&tl[pl][c4 * 4]);
            *(u16x4*)(&xp[((size_t)(px0 + pl)) * C_ + c0 + c4 * 4]) = v4;
        }
        __syncthreads();
    }

#pragma unroll
    for (int kk = 0; kk < 9; ++kk) red[cq][px_l][kk] = pg[kk];
    red[cq][px_l][9] = ps;
    __syncthreads();
    for (int it = t; it < 640; it += 256) {
        int pl = it / 10;
        int j  = it - pl * 10;
        float s = red[0][pl][j] + red[1][pl][j] + red[2][pl][j] + red[3][pl][j];
        int q = px0 + pl;
        if (j < 9) g[(size_t)j * NPIX + q] = s;
        else       s2[q] = s;
    }
}

// ---- Kernel B2 (+A): per-column vote -> histogram; tail blocks do kbucket ---
// grid = NPIX/256 + 8 blocks
__global__ __launch_bounds__(256) void votek_kernel(const float* __restrict__ g,
                                                    const float* __restrict__ s2,
                                                    const float* __restrict__ ah,
                                                    const float* __restrict__ bh,
                                                    const float* __restrict__ kern,
                                                    int* __restrict__ counts,
                                                    int* __restrict__ kbuck) {
    int kb = blockIdx.x - (NPIX / 256);
    if (kb >= 0) {
        // ---- kbucket: 64 oc per block, 4 threads per oc ----
        int t = threadIdx.x;
        int oc_l = t >> 2, part = t & 3;
        int oc = kb * 64 + oc_l;
        const float* kr = kern + (size_t)oc * SPAN_ + part * 576;
        const float* ap = ah + part * 576;
        float dot = 0.f, ss = 0.f;
        for (int i = 0; i < 144; ++i) {
            float4 kv = *(const float4*)(kr + i * 4);
            float4 av = *(const float4*)(ap + i * 4);
            dot += kv.x * av.x + kv.y * av.y + kv.z * av.z + kv.w * av.w;
            ss  += kv.x * kv.x + kv.y * kv.y + kv.z * kv.z + kv.w * kv.w;
        }
        dot += __shfl_xor(dot, 1); dot += __shfl_xor(dot, 2);
        ss  += __shfl_xor(ss, 1);  ss  += __shfl_xor(ss, 2);
        if (part == 0) {
            float n2 = ss;            // ||k||^2
            float n4 = n2 * n2;
            float n8 = n4 * n4;
            float v = dot + n2 * ah[SPAN_] + n4 * ah[SPAN_ + 1] +
                      n8 * ah[SPAN_ + 2];
            kbuck[oc] = bucketf(v, bh[0]);
        }
        return;
    }

    __shared__ int hist[8];
    if (threadIdx.x < 8) hist[threadIdx.x] = 0;
    __syncthreads();
    int q = blockIdx.x * 256 + threadIdx.x;
    int n = q / HW_;
    int p = q - n * HW_;
    int h = p / W_;
    int w = p - h * W_;
    float dot = 0.f, ss = 0.f;
#pragma unroll
    for (int kk = 0; kk < 9; ++kk) {
        int dh = kk / 3 - 1, dw = kk % 3 - 1;
        int hh = h + dh, ww = w + dw;
        if (hh >= 0 && hh < H_ && ww >= 0 && ww < W_) {
            int idx = n * HW_ + hh * W_ + ww;
            dot += g[(size_t)kk * NPIX + idx];
            ss  += s2[idx];
        }
    }
    float qext = 0.5f * (ah[SPAN_] + ah[SPAN_ + 1] + ah[SPAN_ + 2]);
    float v = dot / sqrtf(ss) + qext;
    int b = bucketf(v, bh[0]);
    atomicAdd(&hist[b], 1);
    __syncthreads();
    if (threadIdx.x < 8) atomicAdd(&counts[threadIdx.x], hist[threadIdx.x]);
}

// ---- Kernel C: argmax bucket + ordered compaction (512-thread scan) ---------
__global__ __launch_bounds__(512) void select_kernel(const int* __restrict__ counts,
                                                     const int* __restrict__ kbuck,
                                                     int* __restrict__ rowsb,
                                                     int* __restrict__ meta,
                                                     float* __restrict__ out,
                                                     int oc_total) {
    __shared__ int sBest;
    __shared__ int sScan[512];
    int t = threadIdx.x;
    if (t == 0) {
        int best = 0, bc = counts[0];
        for (int i = 1; i < 8; ++i) {
            int c = counts[i];
            if (c > bc) { bc = c; best = i; }   // first max wins
        }
        sBest = best;
    }
    __syncthreads();
    int best = sBest;
    int flag = (kbuck[t] == best) ? 1 : 0;
    sScan[t] = flag;
    __syncthreads();
    for (int off = 1; off < 512; off <<= 1) {
        int add = (t >= off) ? sScan[t - off] : 0;
        __syncthreads();
        sScan[t] += add;
        __syncthreads();
    }
    int cnt = sScan[511];
    int pos = sScan[t] - flag;                  // exclusive prefix
    if (flag) rowsb[pos] = t;
    if (cnt == 0) rowsb[t] = t;                 // use-all fallback
    else if (t >= cnt) rowsb[t] = 0;            // safety fill
    if (t == 0) {
        meta[0] = cnt;
        meta[1] = (cnt == 0) ? OUTC : cnt;
    }
    float* rout = out + (size_t)N_ * oc_total * HW_;
    int eff = (cnt == 0) ? OUTC : cnt;
    int nw = eff < oc_total ? eff : oc_total;
    if (cnt == 0) {
        if (t < nw) rout[t] = (float)t;
    } else if (flag && pos < nw) {
        rout[pos] = (float)t;
    }
}

// ---- Kernel P2: gather active rows -> MFMA B-fragment order bf16 -------------
__global__ __launch_bounds__(256) void prep_w(const float* __restrict__ kern,
                                              const int* __restrict__ rowsb,
                                              const int* __restrict__ meta,
                                              const int* __restrict__ mode,
                                              u16* __restrict__ wfrag, int nf4) {
    int e = blockIdx.x * 256 + threadIdx.x;
    int lane = e & 63;
    int t2 = e >> 6;
    int g = t2 % nf4;
    int s = t2 / nf4;                    // 0..71
    int kk = s >> 3;
    int cb = s & 7;
    int q = lane >> 4;
    int mcol = lane & 15;
    int ocEff = meta[1];
    int cnt = meta[0];
    float scale = (mode[0] && cnt > 0) ? 512.0f / (float)cnt : 1.0f;
    int oc_i = g * 16 + mcol;
    bool valid = oc_i < ocEff;
    int row = valid ? rowsb[oc_i] : 0;
    const float* kr = kern + (size_t)row * SPAN_;
    u16 w8[8];
#pragma unroll
    for (int j = 0; j < 8; ++j) {
        int c = cb * 32 + q * 8 + j;
        float v = valid ? kr[c * 9 + kk] * scale : 0.f;
        w8[j] = f2bf(v);
    }
    u16* dst = wfrag + ((size_t)((s * nf4 + g) * 64 + lane)) * 8;
#pragma unroll
    for (int j = 0; j < 8; ++j) dst[j] = w8[j];
}

// ---- Kernel D: MFMA implicit-GEMM conv, LDS halo, 2-wave blocks -------------
// block tile = 128 px x 64 oc; halo slot stride 80 B (conflict-free);
// single staging reg set: loads for cb+1 issue right after the read barrier
// and overlap the 9-tap compute.
__global__ __launch_bounds__(128, 4) void conv_mfma(const u16* __restrict__ xp,
                                                    const u16* __restrict__ wfrag,
                                                    float* __restrict__ out,
                                                    int nf4, int oc_total, int nby) {
    __shared__ char halo[HSLOTS * HSTRIDE];        // 20480 B

    // bijective XCD swizzle (grid = 392*nby, 392 % 8 == 0)
    const int tot = (NPIX / BLKPX) * nby;
    const int q8 = tot >> 3;
    const int flat = blockIdx.x;
    const int virt = (flat & 7) * q8 + (flat >> 3);
    const int bx = virt / nby;
    const int by = virt - bx * nby;

    const int t = threadIdx.x;
    const int lane = t & 63;
    const int wv = t >> 6;                         // 0..1
    const int pb = bx * BLKPX;
    const int fb = by * 4;
    const int lane15 = lane & 15;
    const int laneq  = lane >> 4;

    int hA[4], wA[4], aBase[4];
#pragma unroll
    for (int f = 0; f < 4; ++f) {
        int p = pb + wv * 64 + f * 16 + lane15;
        int img = p / HW_;
        int rp = p - img * HW_;
        hA[f] = rp / W_;
        wA[f] = rp - hA[f] * W_;
        aBase[f] = (57 + wv * 64 + f * 16 + lane15) * HSTRIDE + laneq * 16;
    }

    f32x4 acc[4][4];
#pragma unroll
    for (int f = 0; f < 4; ++f)
#pragma unroll
        for (int gg = 0; gg < 4; ++gg) acc[f][gg] = (f32x4){0.f, 0.f, 0.f, 0.f};
    const bf16x8 zf = {0, 0, 0, 0, 0, 0, 0, 0};

    // staging: 8 passes x (32 slots x 4 quarters) by 128 threads
    const int splb = t >> 2;                       // slot sub-index 0..31
    const int sq   = (t & 3) * 16;                 // byte quarter in slot
    const char* xpb = (const char*)xp;
    int gpx[8];
#pragma unroll
    for (int r = 0; r < 8; ++r) {
        int p = pb - 57 + r * 32 + splb;
        gpx[r] = p < 0 ? 0 : (p >= NPIX ? NPIX - 1 : p);
    }

    u16x8 R[8];
#pragma unroll
    for (int r = 0; r < 8; ++r)
        R[r] = *(const u16x8*)(xpb + (size_t)gpx[r] * 512 + sq);

    const size_t kkStride = (size_t)8 * nf4 * 512;

    for (int cb = 0; cb < 8; ++cb) {
        __syncthreads();                           // halo free to overwrite
#pragma unroll
        for (int r = 0; r < 8; ++r)
            *(u16x8*)&halo[(r * 32 + splb) * HSTRIDE + sq] = R[r];
        __syncthreads();                           // halo[cb] ready

        if (cb < 7) {                              // overlap next-cb loads
#pragma unroll
            for (int r = 0; r < 8; ++r)
                R[r] = *(const u16x8*)(xpb + (size_t)gpx[r] * 512 +
                                       (cb + 1) * 64 + sq);
        }

        const u16* wcb = wfrag + ((size_t)cb * nf4 + fb) * 512 + lane * 8;
#pragma unroll
        for (int kk = 0; kk < 9; ++kk) {
            const int dh = kk / 3 - 1, dw = kk % 3 - 1;
            const int toff = (dh * W_ + dw) * HSTRIDE;
            bf16x8 aX[4];
#pragma unroll
            for (int f = 0; f < 4; ++f) {
                int hh = hA[f] + dh, ww = wA[f] + dw;
                bool val = (hh >= 0) & (hh < H_) & (ww >= 0) & (ww < W_);
                bf16x8 a = *(const bf16x8*)&halo[aBase[f] + toff];
                aX[f] = val ? a : zf;
            }
            const u16* wk = wcb + (size_t)kk * kkStride;
            bf16x8 bW[4];
#pragma unroll
            for (int gg = 0; gg < 4; ++gg)
                bW[gg] = *(const bf16x8*)(wk + (size_t)gg * 512);
#pragma unroll
            for (int gg = 0; gg < 4; ++gg)
#pragma unroll
                for (int f = 0; f < 4; ++f)
                    acc[f][gg] = __builtin_amdgcn_mfma_f32_16x16x32_bf16(
                        aX[f], bW[gg], acc[f][gg], 0, 0, 0);
        }
    }

    // epilogue: D row (pixel) = (lane>>4)*4 + r, col (oc) = lane&15
#pragma unroll
    for (int f = 0; f < 4; ++f) {
        int p0 = pb + wv * 64 + f * 16 + laneq * 4;
        int img0 = p0 / HW_;
        int hw0 = p0 - img0 * HW_;
#pragma unroll
        for (int gg = 0; gg < 4; ++gg) {
            int oc = (fb + gg) * 16 + lane15;
            if (oc < oc_total) {
                float* op = out + ((size_t)img0 * oc_total + oc) * HW_ + hw0;
                *(f32x4*)op = acc[f][gg];
            }
        }
    }
}

extern "C" void kernel_launch(void* const* d_in, const int* in_sizes, int n_in,
                              void* d_out, int out_size, void* d_ws, size_t ws_size,
                              hipStream_t stream) {
    const float* x    = (const float*)d_in[0];
    const float* kern = (const float*)d_in[1];
    const float* ah   = (const float*)d_in[2];
    const float* bh   = (const float*)d_in[3];
    const int*   mode = (const int*)d_in[4];
    float* out = (float*)d_out;

    // oc is data-dependent but recoverable from out_size: oc*(16*3136+1)
    int oc_total = (out_size % (N_ * HW_ + 1) == 0) ? out_size / (N_ * HW_ + 1)
                                                    : OUTC;
    int nfTot = (oc_total + 15) / 16;
    int nf4   = ((nfTot + 3) / 4) * 4;       // pad fragments to multiple of 4
    int nby   = nf4 / 4;

    // workspace layout (sized for worst case nf4 = 32)
    u16*   xp     = (u16*)d_ws;                                  // NPIX*256
    u16*   wfrag  = xp + (size_t)NPIX * C_;                      // 72*32*64*8
    float* g      = (float*)(wfrag + (size_t)72 * 32 * 64 * 8);  // 9*NPIX
    float* s2     = g + (size_t)9 * NPIX;                        // NPIX
    int*   counts = (int*)(s2 + NPIX);                           // 8
    int*   kbuck  = counts + 8;                                  // 512
    int*   rowsb  = kbuck + OUTC;                                // 512
    int*   meta   = rowsb + OUTC;                                // 2

    hipMemsetAsync(counts, 0, 8 * sizeof(int), stream);

    prep_fused<<<NPIX / 64, 256, 0, stream>>>(x, ah, xp, g, s2);

    votek_kernel<<<NPIX / 256 + 8, 256, 0, stream>>>(g, s2, ah, bh, kern,
                                                     counts, kbuck);
    select_kernel<<<1, 512, 0, stream>>>(counts, kbuck, rowsb, meta, out, oc_total);

    prep_w<<<18 * nf4, 256, 0, stream>>>(kern, rowsb, meta, mode, wfrag, nf4);

    conv_mfma<<<(NPIX / BLKPX) * nby, 128, 0, stream>>>(xp, wfrag, out, nf4,
                                                        oc_total, nby);
}

// Round 7
// 109.528 us; speedup vs baseline: 1.5304x; 1.5304x over previous
//
#include <hip/hip_runtime.h>
#include <math.h>

#define N_    16
#define C_    256
#define H_    56
#define W_    56
#define HW_   3136          // H_*W_
#define NPIX  50176         // N_*HW_
#define OUTC  512
#define SPAN_ 2304          // C_*9
#define BLKPX 256           // conv block pixel tile
#define HBYTES 24576        // one halo buffer: 384 slots * 64 B

typedef unsigned short u16;
typedef unsigned int   u32;
typedef __attribute__((ext_vector_type(8))) short bf16x8;
typedef __attribute__((ext_vector_type(8))) unsigned short u16x8;
typedef __attribute__((ext_vector_type(4))) float f32x4;
typedef __attribute__((ext_vector_type(4))) unsigned short u16x4;

__device__ __forceinline__ u16 f2bf(float v) {
    u32 x = __float_as_uint(v);
    u32 r = (x + 0x7fffu + ((x >> 16) & 1u)) >> 16;   // RNE
    return (u16)r;
}

__device__ __forceinline__ int bucketf(float v, float b) {
    int idx = (int)floorf((v + b) / 2.5f);
    int r = idx % 8;
    return r < 0 ? -r : r;
}

// ---- Kernel A: bucket of each kernel row ------------------------------------
__global__ void kbucket_kernel(const float* __restrict__ kern,
                               const float* __restrict__ ah,
                               const float* __restrict__ bh,
                               int* __restrict__ kbuck) {
    int oc = blockIdx.x;
    const float* kr = kern + (size_t)oc * SPAN_;
    float dot = 0.f, ss = 0.f;
    for (int j = threadIdx.x; j < SPAN_; j += 64) {
        float kv = kr[j];
        dot += kv * ah[j];
        ss  += kv * kv;
    }
    for (int o = 32; o; o >>= 1) {
        dot += __shfl_down(dot, o);
        ss  += __shfl_down(ss, o);
    }
    if (threadIdx.x == 0) {
        float n2 = ss;            // ||k||^2
        float n4 = n2 * n2;
        float n8 = n4 * n4;
        float v = dot + n2 * ah[SPAN_] + n4 * ah[SPAN_ + 1] + n8 * ah[SPAN_ + 2];
        kbuck[oc] = bucketf(v, bh[0]);
    }
}

// ---- Kernel P1+B1 fused: NCHW f32 -> NHWC bf16, tap maps g[9], sumsq s2 -----
__global__ __launch_bounds__(256) void prep_fused(const float* __restrict__ x,
                                                  const float* __restrict__ ah,
                                                  u16* __restrict__ xp,
                                                  float* __restrict__ g,
                                                  float* __restrict__ s2) {
    __shared__ float aL[SPAN_];          // 9216 B
    __shared__ u16 tl[64][68];           // 8704 B
    __shared__ float red[4][64][10];     // 10240 B
    int t = threadIdx.x;
    for (int j = t; j < SPAN_; j += 256) aL[j] = ah[j];

    int px0 = blockIdx.x * 64;
    int img = px0 / HW_;
    int hw0 = px0 - img * HW_;
    int px_l = t & 63;
    int cq   = t >> 6;                   // 0..3
    float pg[9];
#pragma unroll
    for (int kk = 0; kk < 9; ++kk) pg[kk] = 0.f;
    float ps = 0.f;
    __syncthreads();

    for (int cb0 = 0; cb0 < 4; ++cb0) {
        int c0 = cb0 * 64;
#pragma unroll
        for (int rep = 0; rep < 16; ++rep) {
            int c_l = rep * 4 + cq;
            float v = x[((size_t)(img * C_ + c0 + c_l)) * HW_ + hw0 + px_l];
            tl[px_l][c_l] = f2bf(v);
            const float* ac = &aL[(c0 + c_l) * 9];
#pragma unroll
            for (int kk = 0; kk < 9; ++kk) pg[kk] += ac[kk] * v;
            ps += v * v;
        }
        __syncthreads();
        int c4  = t & 15;
        int pxs = t >> 4;
#pragma unroll
        for (int rep = 0; rep < 4; ++rep) {
            int pl = rep * 16 + pxs;
            u16x4 v4 = *(const u16x4*)(&tl[pl][c4 * 4]);
            *(u16x4*)(&xp[((size_t)(px0 + pl)) * C_ + c0 + c4 * 4]) = v4;
        }
        __syncthreads();
    }

#pragma unroll
    for (int kk = 0; kk < 9; ++kk) red[cq][px_l][kk] = pg[kk];
    red[cq][px_l][9] = ps;
    __syncthreads();
    for (int it = t; it < 640; it += 256) {
        int pl = it / 10;
        int j  = it - pl * 10;
        float s = red[0][pl][j] + red[1][pl][j] + red[2][pl][j] + red[3][pl][j];
        int q = px0 + pl;
        if (j < 9) g[(size_t)j * NPIX + q] = s;
        else       s2[q] = s;
    }
}

// ---- Kernel B2: per-column vote -> histogram --------------------------------
__global__ __launch_bounds__(256) void vote_kernel(const float* __restrict__ g,
                                                   const float* __restrict__ s2,
                                                   const float* __restrict__ ah,
                                                   const float* __restrict__ bh,
                                                   int* __restrict__ counts) {
    __shared__ int hist[8];
    if (threadIdx.x < 8) hist[threadIdx.x] = 0;
    __syncthreads();
    int q = blockIdx.x * 256 + threadIdx.x;
    int n = q / HW_;
    int p = q - n * HW_;
    int h = p / W_;
    int w = p - h * W_;
    float dot = 0.f, ss = 0.f;
#pragma unroll
    for (int kk = 0; kk < 9; ++kk) {
        int dh = kk / 3 - 1, dw = kk % 3 - 1;
        int hh = h + dh, ww = w + dw;
        if (hh >= 0 && hh < H_ && ww >= 0 && ww < W_) {
            int idx = n * HW_ + hh * W_ + ww;
            dot += g[(size_t)kk * NPIX + idx];
            ss  += s2[idx];
        }
    }
    float qext = 0.5f * (ah[SPAN_] + ah[SPAN_ + 1] + ah[SPAN_ + 2]);
    float v = dot / sqrtf(ss) + qext;
    int b = bucketf(v, bh[0]);
    atomicAdd(&hist[b], 1);
    __syncthreads();
    if (threadIdx.x < 8) atomicAdd(&counts[threadIdx.x], hist[threadIdx.x]);
}

// ---- Kernel C: argmax bucket + ordered compaction (512-thread scan) ---------
__global__ __launch_bounds__(512) void select_kernel(const int* __restrict__ counts,
                                                     const int* __restrict__ kbuck,
                                                     int* __restrict__ rowsb,
                                                     int* __restrict__ meta,
                                                     float* __restrict__ out,
                                                     int oc_total) {
    __shared__ int sBest;
    __shared__ int sScan[512];
    int t = threadIdx.x;
    if (t == 0) {
        int best = 0, bc = counts[0];
        for (int i = 1; i < 8; ++i) {
            int c = counts[i];
            if (c > bc) { bc = c; best = i; }   // first max wins
        }
        sBest = best;
    }
    __syncthreads();
    int best = sBest;
    int flag = (kbuck[t] == best) ? 1 : 0;
    sScan[t] = flag;
    __syncthreads();
    for (int off = 1; off < 512; off <<= 1) {
        int add = (t >= off) ? sScan[t - off] : 0;
        __syncthreads();
        sScan[t] += add;
        __syncthreads();
    }
    int cnt = sScan[511];
    int pos = sScan[t] - flag;                  // exclusive prefix
    if (flag) rowsb[pos] = t;
    if (cnt == 0) rowsb[t] = t;                 // use-all fallback
    else if (t >= cnt) rowsb[t] = 0;            // safety fill
    if (t == 0) {
        meta[0] = cnt;
        meta[1] = (cnt == 0) ? OUTC : cnt;
    }
    float* rout = out + (size_t)N_ * oc_total * HW_;
    int eff = (cnt == 0) ? OUTC : cnt;
    int nw = eff < oc_total ? eff : oc_total;
    if (cnt == 0) {
        if (t < nw) rout[t] = (float)t;
    } else if (flag && pos < nw) {
        rout[pos] = (float)t;
    }
}

// ---- Kernel P2: gather active rows -> MFMA B-fragment order bf16 -------------
__global__ __launch_bounds__(256) void prep_w(const float* __restrict__ kern,
                                              const int* __restrict__ rowsb,
                                              const int* __restrict__ meta,
                                              const int* __restrict__ mode,
                                              u16* __restrict__ wfrag, int nf4) {
    int e = blockIdx.x * 256 + threadIdx.x;
    int lane = e & 63;
    int t2 = e >> 6;
    int g = t2 % nf4;
    int s = t2 / nf4;                    // 0..71
    int kk = s >> 3;
    int cb = s & 7;
    int q = lane >> 4;
    int mcol = lane & 15;
    int ocEff = meta[1];
    int cnt = meta[0];
    float scale = (mode[0] && cnt > 0) ? 512.0f / (float)cnt : 1.0f;
    int oc_i = g * 16 + mcol;
    bool valid = oc_i < ocEff;
    int row = valid ? rowsb[oc_i] : 0;
    const float* kr = kern + (size_t)row * SPAN_;
    u16 w8[8];
#pragma unroll
    for (int j = 0; j < 8; ++j) {
        int c = cb * 32 + q * 8 + j;
        float v = valid ? kr[c * 9 + kk] * scale : 0.f;
        w8[j] = f2bf(v);
    }
    u16* dst = wfrag + ((size_t)((s * nf4 + g) * 64 + lane)) * 8;
#pragma unroll
    for (int j = 0; j < 8; ++j) dst[j] = w8[j];
}

// ---- Kernel D: MFMA implicit-GEMM conv --------------------------------------
// 4 waves/block, block tile 256 px x 64 oc. A staged via global_load_lds into a
// double-buffered LDS halo (1 barrier per 32-ch step); B software-pipelined one
// kk ahead in registers.
__global__ __launch_bounds__(256, 2) void conv_mfma(const u16* __restrict__ xp,
                                                    const u16* __restrict__ wfrag,
                                                    float* __restrict__ out,
                                                    int nf4, int oc_total, int nby) {
    __shared__ char halo[2 * HBYTES];              // 49152 B

    // XCD swizzle: oc-sibling blocks co-located on one XCD; 196 bx = 24*8 + 4.
    int flat = blockIdx.x;
    int bx, by;
    int full = 192 * nby;
    if (flat < full) {
        int gsz = 8 * nby;
        int gi = flat / gsz;
        int tr = flat - gi * gsz;
        by = tr >> 3;
        bx = gi * 8 + (tr & 7);
    } else {
        int tr = flat - full;
        by = tr >> 2;
        bx = 192 + (tr & 3);
    }

    const int t = threadIdx.x;
    const int lane = t & 63;
    const int wv = t >> 6;                         // 0..3
    const int pb = bx * BLKPX;
    const int fb = by * 4;
    const int lane15 = lane & 15;
    const int laneq  = lane >> 4;

    int hA[4], wA[4], aBase[4];
#pragma unroll
    for (int f = 0; f < 4; ++f) {
        int p = pb + wv * 64 + f * 16 + lane15;
        int img = p / HW_;
        int rp = p - img * HW_;
        hA[f] = rp / W_;
        wA[f] = rp - hA[f] * W_;
        aBase[f] = (57 + wv * 64 + f * 16 + lane15) * 64 + laneq * 16;
    }

    f32x4 acc[4][4];
#pragma unroll
    for (int f = 0; f < 4; ++f)
#pragma unroll
        for (int gg = 0; gg < 4; ++gg) acc[f][gg] = (f32x4){0.f, 0.f, 0.f, 0.f};
    const bf16x8 zf = {0, 0, 0, 0, 0, 0, 0, 0};

    // staging: 6 global_load_lds_dwordx4 per thread; LDS dest = linear t*16
    const char* xpb = (const char*)xp;
    const char* gsrc[6];
#pragma unroll
    for (int r = 0; r < 6; ++r) {
        int p = pb - 57 + r * 64 + (t >> 2);
        p = p < 0 ? 0 : (p >= NPIX ? NPIX - 1 : p);
        gsrc[r] = xpb + (size_t)p * 512 + (t & 3) * 16;
    }

    // prologue: issue staging for cb = 0 into buf 0
#pragma unroll
    for (int r = 0; r < 6; ++r)
        __builtin_amdgcn_global_load_lds(
            (const __attribute__((address_space(1))) unsigned int*)(gsrc[r]),
            (__attribute__((address_space(3))) unsigned int*)&halo[r * 4096 + t * 16],
            16, 0, 0);

    const size_t kkStride = (size_t)8 * nf4 * 512;

    for (int cb = 0; cb < 8; ++cb) {
        __syncthreads();   // per-wave vmcnt drain before barrier -> buf[cb&1] ready
        const char* hb = &halo[(cb & 1) * HBYTES];

        if (cb < 7) {      // issue next-cb staging into the other buffer
            char* hn = &halo[((cb + 1) & 1) * HBYTES];
#pragma unroll
            for (int r = 0; r < 6; ++r)
                __builtin_amdgcn_global_load_lds(
                    (const __attribute__((address_space(1))) unsigned int*)
                        (gsrc[r] + (cb + 1) * 64),
                    (__attribute__((address_space(3))) unsigned int*)
                        &hn[r * 4096 + t * 16],
                    16, 0, 0);
        }

        const u16* wcb = wfrag + ((size_t)cb * nf4 + fb) * 512 + lane * 8;
        bf16x8 bW[4];
#pragma unroll
        for (int gg = 0; gg < 4; ++gg)
            bW[gg] = *(const bf16x8*)(wcb + (size_t)gg * 512);   // kk = 0

#pragma unroll
        for (int kk = 0; kk < 9; ++kk) {
            bf16x8 bWn[4];
            if (kk < 8) {                           // prefetch next kk's B
                const u16* wn = wcb + (size_t)(kk + 1) * kkStride;
#pragma unroll
                for (int gg = 0; gg < 4; ++gg)
                    bWn[gg] = *(const bf16x8*)(wn + (size_t)gg * 512);
            }
            const int dh = kk / 3 - 1, dw = kk % 3 - 1;
            const int toff = (dh * W_ + dw) * 64;
            bf16x8 aX[4];
#pragma unroll
            for (int f = 0; f < 4; ++f) {
                int hh = hA[f] + dh, ww = wA[f] + dw;
                bool val = (hh >= 0) & (hh < H_) & (ww >= 0) & (ww < W_);
                bf16x8 a = *(const bf16x8*)&hb[aBase[f] + toff];
                aX[f] = val ? a : zf;
            }
#pragma unroll
            for (int gg = 0; gg < 4; ++gg)
#pragma unroll
                for (int f = 0; f < 4; ++f)
                    acc[f][gg] = __builtin_amdgcn_mfma_f32_16x16x32_bf16(
                        aX[f], bW[gg], acc[f][gg], 0, 0, 0);
            if (kk < 8) {
#pragma unroll
                for (int gg = 0; gg < 4; ++gg) bW[gg] = bWn[gg];
            }
        }
    }

    // epilogue: D row (pixel) = (lane>>4)*4 + r, col (oc) = lane&15
#pragma unroll
    for (int f = 0; f < 4; ++f) {
        int p0 = pb + wv * 64 + f * 16 + laneq * 4;
        int img0 = p0 / HW_;
        int hw0 = p0 - img0 * HW_;
#pragma unroll
        for (int gg = 0; gg < 4; ++gg) {
            int oc = (fb + gg) * 16 + lane15;
            if (oc < oc_total) {
                float* op = out + ((size_t)img0 * oc_total + oc) * HW_ + hw0;
                *(f32x4*)op = acc[f][gg];
            }
        }
    }
}

extern "C" void kernel_launch(void* const* d_in, const int* in_sizes, int n_in,
                              void* d_out, int out_size, void* d_ws, size_t ws_size,
                              hipStream_t stream) {
    const float* x    = (const float*)d_in[0];
    const float* kern = (const float*)d_in[1];
    const float* ah   = (const float*)d_in[2];
    const float* bh   = (const float*)d_in[3];
    const int*   mode = (const int*)d_in[4];
    float* out = (float*)d_out;

    // oc is data-dependent but recoverable from out_size: oc*(16*3136+1)
    int oc_total = (out_size % (N_ * HW_ + 1) == 0) ? out_size / (N_ * HW_ + 1)
                                                    : OUTC;
    int nfTot = (oc_total + 15) / 16;
    int nf4   = ((nfTot + 3) / 4) * 4;       // pad fragments to multiple of 4
    int nby   = nf4 / 4;

    // workspace layout (sized for worst case nf4 = 32)
    u16*   xp     = (u16*)d_ws;                                  // NPIX*256
    u16*   wfrag  = xp + (size_t)NPIX * C_;                      // 72*32*64*8
    float* g      = (float*)(wfrag + (size_t)72 * 32 * 64 * 8);  // 9*NPIX
    float* s2     = g + (size_t)9 * NPIX;                        // NPIX
    int*   counts = (int*)(s2 + NPIX);                           // 8
    int*   kbuck  = counts + 8;                                  // 512
    int*   rowsb  = kbuck + OUTC;                                // 512
    int*   meta   = rowsb + OUTC;                                // 2

    hipMemsetAsync(counts, 0, 8 * sizeof(int), stream);

    prep_fused<<<NPIX / 64, 256, 0, stream>>>(x, ah, xp, g, s2);

    kbucket_kernel<<<OUTC, 64, 0, stream>>>(kern, ah, bh, kbuck);
    vote_kernel<<<NPIX / 256, 256, 0, stream>>>(g, s2, ah, bh, counts);
    select_kernel<<<1, 512, 0, stream>>>(counts, kbuck, rowsb, meta, out, oc_total);

    prep_w<<<18 * nf4, 256, 0, stream>>>(kern, rowsb, meta, mode, wfrag, nf4);

    conv_mfma<<<(NPIX / BLKPX) * nby, 256, 0, stream>>>(xp, wfrag, out, nf4,
                                                        oc_total, nby);
}